// Round 12
// baseline (1117.116 us; speedup 1.0000x reference)
//
#include <hip/hip_runtime.h>

#define TT 2048
#define BB 64

typedef _Float16 v2h __attribute__((ext_vector_type(2)));
typedef _Float16 v4h __attribute__((ext_vector_type(4)));
typedef float v4f __attribute__((ext_vector_type(4)));

__device__ __forceinline__ float frcp(float x) { return __builtin_amdgcn_rcpf(x); }
__device__ __forceinline__ float fsig(float x) { return frcp(1.f + __expf(-x)); }
__device__ __forceinline__ float ftan(float x) { return 1.f - 2.f * frcp(1.f + __expf(2.f * x)); }

#if __has_builtin(__builtin_amdgcn_fdot2)
#define FDOT2(a, b, c) __builtin_amdgcn_fdot2((a), (b), (c), false)
#else
#define FDOT2(a, b, c) ((c) + (float)(a).x * (float)(b).x + (float)(a).y * (float)(b).y)
#endif

// Canonical GCN wave64 sum-reduction via DPP (verified R4..R11).
#define DPPADD(x, ctrl)                                                        \
  (x) += __builtin_bit_cast(float, __builtin_amdgcn_update_dpp(                \
             0, __builtin_bit_cast(int, (x)), (ctrl), 0xf, 0xf, true))

__device__ __forceinline__ float wave_sum64(float x) {
  DPPADD(x, 0x111);  // row_shr:1
  DPPADD(x, 0x112);  // row_shr:2
  DPPADD(x, 0x114);  // row_shr:4
  DPPADD(x, 0x118);  // row_shr:8
  DPPADD(x, 0x142);  // row_bcast:15
  DPPADD(x, 0x143);  // row_bcast:31
  return __builtin_bit_cast(
      float, __builtin_amdgcn_readlane(__builtin_bit_cast(int, x), 63));
}

// MFMA gates GEMM + fused P: (R11-proven MFMA structure)
//   G[(b*Tc+tt)*256+g] = X_row . W_ih[g,:256] + bih[g]+bhh[g]   (fp16 MFMA)
//   P[b*Tc+tt]         = X_row . w21 + bias2                    (fp32, fused)
// P is accumulated from the fp32 register copies of X made during staging
// (blockIdx.y==0 only) -> eliminates the separate 134MB X re-read pz_kernel.
// Legacy v_mfma_f32_16x16x16f16; tile M=64 x N=128; K-chunks of 32 in LDS
// (row stride 40 fp16 -> 2-way conflicts only). grid=(Tc,2), block=256.
__global__ __launch_bounds__(256) void gates_gemm_mfma(
    const float* __restrict__ X, const float* __restrict__ W,
    const float* __restrict__ bih, const float* __restrict__ bhh,
    const float* __restrict__ w21, const float* __restrict__ bias2,
    float* __restrict__ G, float* __restrict__ P, int t0, int Tc) {
  __shared__ __align__(16) _Float16 Xs[64][40];
  __shared__ __align__(16) _Float16 Ws[128][40];
  __shared__ float w21s[256];
  const int tid = threadIdx.x;
  const int m0 = blockIdx.x * 64;
  const int n0 = blockIdx.y * 128;
  const int bb = m0 / Tc;
  const int tt0 = m0 - bb * Tc;
  const int w = tid >> 6, l = tid & 63;
  const int lr = l & 15, lk = l >> 4;
  const bool do_pz = (blockIdx.y == 0);

  const int srow = tid >> 2, skq = (tid & 3) * 8;
  const int wri = tid >> 1, wkh = (tid & 1) * 16;
  const float* xrow = X + (size_t)(bb * TT + t0 + tt0 + srow) * 256 + skq;
  const float* wrow = W + (size_t)(n0 + wri) * 257 + wkh;

  w21s[tid] = w21[tid];

  float bsum[8];
#pragma unroll
  for (int nf = 0; nf < 8; ++nf)
    bsum[nf] = bih[n0 + nf * 16 + lr] + bhh[n0 + nf * 16 + lr];

  v4f acc[8];
#pragma unroll
  for (int nf = 0; nf < 8; ++nf) acc[nf] = (v4f){0.f, 0.f, 0.f, 0.f};
  float psum = 0.f;

  for (int k0 = 0; k0 < 256; k0 += 32) {
    float xa[8], wa[16];
#pragma unroll
    for (int u = 0; u < 8; ++u) xa[u] = xrow[k0 + u];
#pragma unroll
    for (int u = 0; u < 16; ++u) wa[u] = wrow[k0 + u];
    if (k0 != 0) __syncthreads();
    {
      uint xw[4];
#pragma unroll
      for (int u = 0; u < 4; ++u) {
        v2h p; p.x = (_Float16)xa[2*u]; p.y = (_Float16)xa[2*u+1];
        xw[u] = __builtin_bit_cast(uint, p);
      }
      *reinterpret_cast<uint4*>(&Xs[srow][skq]) =
          make_uint4(xw[0], xw[1], xw[2], xw[3]);
      uint ww[8];
#pragma unroll
      for (int u = 0; u < 8; ++u) {
        v2h p; p.x = (_Float16)wa[2*u]; p.y = (_Float16)wa[2*u+1];
        ww[u] = __builtin_bit_cast(uint, p);
      }
      *reinterpret_cast<uint4*>(&Ws[wri][wkh]) =
          make_uint4(ww[0], ww[1], ww[2], ww[3]);
      *reinterpret_cast<uint4*>(&Ws[wri][wkh + 8]) =
          make_uint4(ww[4], ww[5], ww[6], ww[7]);
    }
    __syncthreads();
    if (do_pz) {
#pragma unroll
      for (int u = 0; u < 8; ++u) psum += xa[u] * w21s[k0 + skq + u];
    }
    const v4h a0 = *reinterpret_cast<const v4h*>(&Xs[w * 16 + lr][lk * 4]);
    const v4h a1 = *reinterpret_cast<const v4h*>(&Xs[w * 16 + lr][16 + lk * 4]);
#pragma unroll
    for (int nf = 0; nf < 8; ++nf) {
      const v4h b0 = *reinterpret_cast<const v4h*>(&Ws[nf * 16 + lr][lk * 4]);
      const v4h b1 = *reinterpret_cast<const v4h*>(&Ws[nf * 16 + lr][16 + lk * 4]);
      acc[nf] = __builtin_amdgcn_mfma_f32_16x16x16f16(a0, b0, acc[nf], 0, 0, 0);
      acc[nf] = __builtin_amdgcn_mfma_f32_16x16x16f16(a1, b1, acc[nf], 0, 0, 0);
    }
  }
  if (do_pz) {
    psum += __shfl_xor(psum, 1);
    psum += __shfl_xor(psum, 2);
    if ((tid & 3) == 0) P[m0 + srow] = psum + bias2[0];
  }
  const int grow = m0 + w * 16 + lk * 4;
#pragma unroll
  for (int nf = 0; nf < 8; ++nf) {
#pragma unroll
    for (int j = 0; j < 4; ++j) {
      G[(size_t)(grow + j) * 256 + n0 + nf * 16 + lr] = acc[nf][j] + bsum[nf];
    }
  }
}

// Serial recurrence: ONE WAVE PER BLOCK (R9/R11 structure, 951us measured).
// Change vs R11: dot chains split 2x16-deep -> 4x8-deep per gate (16 indep
// accumulators) to cut exposed FDOT2 dependency latency.
__global__ __launch_bounds__(64, 1) void lstm_seq8(
    const float* __restrict__ G, const float* __restrict__ P,
    const float* __restrict__ Wih, const float* __restrict__ Whh,
    const float* __restrict__ w22, float* __restrict__ Z,
    float* __restrict__ hq, float* __restrict__ cq, int t0, int Tc) {
  const int l = threadIdx.x;         // hidden unit
  const int b = blockIdx.x;          // batch row
  __shared__ __align__(16) _Float16 hsm[64];

  v2h wh[4][32];
#pragma unroll
  for (int q = 0; q < 4; ++q) {
#pragma unroll
    for (int j = 0; j < 16; ++j) {
      float4 v = *reinterpret_cast<const float4*>(&Whh[(size_t)(q*64 + l)*64 + 4*j]);
      v2h pA, pB;
      pA.x = (_Float16)v.x; pA.y = (_Float16)v.y;
      pB.x = (_Float16)v.z; pB.y = (_Float16)v.w;
      wh[q][2*j] = pA; wh[q][2*j+1] = pB;
    }
  }
  float wihL[4];
#pragma unroll
  for (int q = 0; q < 4; ++q) wihL[q] = Wih[(size_t)(q*64 + l)*257 + 256];
  const float w22r = w22[l];

  float h = 0.f, c = 0.f;
  if (t0 != 0) { h = hq[b * 64 + l]; c = cq[b * 64 + l]; }
  hsm[l] = (_Float16)h;
  __builtin_amdgcn_wave_barrier();

  const float* Gb = G + (size_t)b * Tc * 256 + l;
  const float* Pb = P + (size_t)b * Tc;
  float* Zb = Z + (size_t)b * TT + t0;

  float gr[4][4], pr[4];
#pragma unroll
  for (int u = 0; u < 4; ++u) {
    const float* Gt = Gb + (size_t)u * 256;
#pragma unroll
    for (int q = 0; q < 4; ++q) gr[u][q] = Gt[q * 64];
    pr[u] = Pb[u];
  }

  for (int tt = 0; tt < Tc; tt += 4) {
    float zs[4];
#pragma unroll
    for (int uu = 0; uu < 4; ++uu) {
      const int step = tt + uu;
      const float gx0 = gr[uu][0], gx1 = gr[uu][1];
      const float gx2 = gr[uu][2], gx3 = gr[uu][3];
      const float p0 = pr[uu];
      int pf = step + 4; if (pf > Tc - 1) pf = Tc - 1;
      {
        const float* Gt = Gb + (size_t)pf * 256;
#pragma unroll
        for (int q = 0; q < 4; ++q) gr[uu][q] = Gt[q * 64];
        pr[uu] = Pb[pf];
      }

      const float tot = wave_sum64(h * w22r);
      const float pz = fsig(tot + p0);

      // 4 gate dots, each as 4 independent 8-deep FDOT2 chains
      float d0[4] = {0.f,0.f,0.f,0.f}, d1[4] = {0.f,0.f,0.f,0.f};
      float d2[4] = {0.f,0.f,0.f,0.f}, d3[4] = {0.f,0.f,0.f,0.f};
      const uint4* hp = reinterpret_cast<const uint4*>(hsm);
#pragma unroll
      for (int jj = 0; jj < 8; ++jj) {
        const uint4 uq = hp[jj];
        const v2h ha = __builtin_bit_cast(v2h, uq.x);
        const v2h hb = __builtin_bit_cast(v2h, uq.y);
        const v2h hc = __builtin_bit_cast(v2h, uq.z);
        const v2h hd = __builtin_bit_cast(v2h, uq.w);
        d0[0] = FDOT2(ha, wh[0][4*jj+0], d0[0]); d0[1] = FDOT2(hb, wh[0][4*jj+1], d0[1]);
        d0[2] = FDOT2(hc, wh[0][4*jj+2], d0[2]); d0[3] = FDOT2(hd, wh[0][4*jj+3], d0[3]);
        d1[0] = FDOT2(ha, wh[1][4*jj+0], d1[0]); d1[1] = FDOT2(hb, wh[1][4*jj+1], d1[1]);
        d1[2] = FDOT2(hc, wh[1][4*jj+2], d1[2]); d1[3] = FDOT2(hd, wh[1][4*jj+3], d1[3]);
        d2[0] = FDOT2(ha, wh[2][4*jj+0], d2[0]); d2[1] = FDOT2(hb, wh[2][4*jj+1], d2[1]);
        d2[2] = FDOT2(hc, wh[2][4*jj+2], d2[2]); d2[3] = FDOT2(hd, wh[2][4*jj+3], d2[3]);
        d3[0] = FDOT2(ha, wh[3][4*jj+0], d3[0]); d3[1] = FDOT2(hb, wh[3][4*jj+1], d3[1]);
        d3[2] = FDOT2(hc, wh[3][4*jj+2], d3[2]); d3[3] = FDOT2(hd, wh[3][4*jj+3], d3[3]);
      }
      const float pre0 = gx0 + pz * wihL[0] + ((d0[0]+d0[1]) + (d0[2]+d0[3]));
      const float pre1 = gx1 + pz * wihL[1] + ((d1[0]+d1[1]) + (d1[2]+d1[3]));
      const float pre2 = gx2 + pz * wihL[2] + ((d2[0]+d2[1]) + (d2[2]+d2[3]));
      const float pre3 = gx3 + pz * wihL[3] + ((d3[0]+d3[1]) + (d3[2]+d3[3]));

      const float ai = fsig(pre0);
      const float af = fsig(pre1);
      const float ag = ftan(pre2);
      const float ao = fsig(pre3);
      c = af * c + ai * ag;
      h = ao * ftan(c);

      __builtin_amdgcn_wave_barrier();
      hsm[l] = (_Float16)h;
      __builtin_amdgcn_wave_barrier();
      zs[uu] = pz;
    }
    if (l == 0) {
      float4 zo; zo.x = zs[0]; zo.y = zs[1]; zo.z = zs[2]; zo.w = zs[3];
      *reinterpret_cast<float4*>(&Zb[tt]) = zo;
    }
  }
  hq[b * 64 + l] = h;
  cq[b * 64 + l] = c;
}

// Fully-inline fp32 fallback (only if d_ws is too small for a 64-step chunk).
__global__ __launch_bounds__(256) void lstm_fallback(const float* __restrict__ X,
    const float* __restrict__ w21, const float* __restrict__ w22,
    const float* __restrict__ bias2, const float* __restrict__ Wih,
    const float* __restrict__ Whh, const float* __restrict__ bih,
    const float* __restrict__ bhh, float* __restrict__ Z) {
  const int b = blockIdx.x;
  const int g = threadIdx.x;
  const int lane = g & 63;
  __shared__ __align__(16) float h_s[64];
  __shared__ float act_s[256];
  __shared__ __align__(16) float x_s[256];
  __shared__ __align__(16) float w21_s[256];
  float wh[64];
#pragma unroll
  for (int j = 0; j < 64; j += 4) {
    float4 v = *reinterpret_cast<const float4*>(&Whh[(size_t)g*64 + j]);
    wh[j]=v.x; wh[j+1]=v.y; wh[j+2]=v.z; wh[j+3]=v.w;
  }
  const float wihL = Wih[(size_t)g*257 + 256];
  const float bias = bih[g] + bhh[g];
  const float b2 = bias2[0];
  const float w22r = w22[lane];
  w21_s[g] = w21[g];
  if (g < 64) h_s[g] = 0.f;
  float c = 0.f;
  __syncthreads();
  const float* Wr = Wih + (size_t)g * 257;
  for (int t = 0; t < TT; ++t) {
    x_s[g] = X[((size_t)b*TT + t)*256 + g];
    __syncthreads();
    float pv = h_s[lane] * w22r;
    {
      const float4 xq = *reinterpret_cast<const float4*>(&x_s[lane*4]);
      const float4 wq = *reinterpret_cast<const float4*>(&w21_s[lane*4]);
      pv += xq.x*wq.x + xq.y*wq.y + xq.z*wq.z + xq.w*wq.w;
    }
#pragma unroll
    for (int o = 32; o; o >>= 1) pv += __shfl_xor(pv, o);
    const float pz = fsig(pv + b2);
    float a0=0.f, a1=0.f, a2=0.f, a3=0.f;
#pragma unroll
    for (int j = 0; j < 64; j += 4) {
      float4 hv = *reinterpret_cast<const float4*>(&h_s[j]);
      a0 += hv.x*wh[j]; a1 += hv.y*wh[j+1]; a2 += hv.z*wh[j+2]; a3 += hv.w*wh[j+3];
    }
    float xd0=0.f, xd1=0.f, xd2=0.f, xd3=0.f;
    for (int k = 0; k < 256; k += 4) {
      const float4 xq = *reinterpret_cast<const float4*>(&x_s[k]);
      xd0 += xq.x*Wr[k]; xd1 += xq.y*Wr[k+1]; xd2 += xq.z*Wr[k+2]; xd3 += xq.w*Wr[k+3];
    }
    const float pre = bias + pz*wihL + ((a0+a1)+(a2+a3)) + ((xd0+xd1)+(xd2+xd3));
    act_s[g] = ((g >> 6) == 2) ? ftan(pre) : fsig(pre);
    if (g == 0) Z[(size_t)b*TT + t] = pz;
    __syncthreads();
    if (g < 64) {
      const float iv = act_s[g], fv = act_s[64+g], gv = act_s[128+g], ov = act_s[192+g];
      c = fv*c + iv*gv;
      h_s[g] = ov * ftan(c);
    }
    __syncthreads();
  }
}

extern "C" void kernel_launch(void* const* d_in, const int* in_sizes, int n_in,
                              void* d_out, int out_size, void* d_ws, size_t ws_size,
                              hipStream_t stream) {
  const float* X     = (const float*)d_in[0];  // [64,2048,256]
  const float* w21   = (const float*)d_in[1];  // [256]
  const float* w22   = (const float*)d_in[2];  // [64]
  const float* bias2 = (const float*)d_in[3];  // [1]
  const float* Wih   = (const float*)d_in[4];  // [256,257]
  const float* Whh   = (const float*)d_in[5];  // [256,64]
  const float* bih   = (const float*)d_in[6];  // [256]
  const float* bhh   = (const float*)d_in[7];  // [256]
  float* Z = (float*)d_out;                    // [64,2048]

  int Tc = 0;
  for (int cand = 2048; cand >= 64; cand >>= 1) {
    size_t need = (size_t)cand * (64*256*4 + 64*4) + 2*64*64*4;
    if (ws_size >= need) { Tc = cand; break; }
  }
  if (Tc == 0) {
    lstm_fallback<<<dim3(64), dim3(256), 0, stream>>>(X, w21, w22, bias2, Wih, Whh, bih, bhh, Z);
    return;
  }
  float* Gbuf = (float*)d_ws;                       // [64*Tc, 256]
  float* Pbuf = Gbuf + (size_t)64 * Tc * 256;       // [64*Tc]
  float* hq   = Pbuf + (size_t)64 * Tc;             // [64,64]
  float* cq   = hq + 64 * 64;                       // [64,64]
  for (int t0 = 0; t0 < 2048; t0 += Tc) {
    gates_gemm_mfma<<<dim3(Tc, 2), dim3(256), 0, stream>>>(
        X, Wih, bih, bhh, w21, bias2, Gbuf, Pbuf, t0, Tc);
    lstm_seq8<<<dim3(BB), dim3(64), 0, stream>>>(
        Gbuf, Pbuf, Wih, Whh, w22, Z, hq, cq, t0, Tc);
  }
}

// Round 13
// 1047.782 us; speedup vs baseline: 1.0662x; 1.0662x over previous
//
#include <hip/hip_runtime.h>

#define TT 2048
#define BB 64

typedef _Float16 v2h __attribute__((ext_vector_type(2)));
typedef _Float16 v4h __attribute__((ext_vector_type(4)));
typedef float v4f __attribute__((ext_vector_type(4)));

__device__ __forceinline__ float frcp(float x) { return __builtin_amdgcn_rcpf(x); }
__device__ __forceinline__ float fsig(float x) { return frcp(1.f + __expf(-x)); }
__device__ __forceinline__ float ftan(float x) { return 1.f - 2.f * frcp(1.f + __expf(2.f * x)); }

#if __has_builtin(__builtin_amdgcn_fdot2)
#define FDOT2(a, b, c) __builtin_amdgcn_fdot2((a), (b), (c), false)
#else
#define FDOT2(a, b, c) ((c) + (float)(a).x * (float)(b).x + (float)(a).y * (float)(b).y)
#endif

// Canonical GCN wave64 sum-reduction via DPP (verified R4..R12).
#define DPPADD(x, ctrl)                                                        \
  (x) += __builtin_bit_cast(float, __builtin_amdgcn_update_dpp(                \
             0, __builtin_bit_cast(int, (x)), (ctrl), 0xf, 0xf, true))

__device__ __forceinline__ float wave_sum64(float x) {
  DPPADD(x, 0x111);  // row_shr:1
  DPPADD(x, 0x112);  // row_shr:2
  DPPADD(x, 0x114);  // row_shr:4
  DPPADD(x, 0x118);  // row_shr:8
  DPPADD(x, 0x142);  // row_bcast:15
  DPPADD(x, 0x143);  // row_bcast:31
  return __builtin_bit_cast(
      float, __builtin_amdgcn_readlane(__builtin_bit_cast(int, x), 63));
}

// MFMA gates GEMM + fused P (both proven: MFMA R11, fusion R12):
//   G[(b*Tc+tt)*256+g] = X_row . W_ih[g,:256] + bih[g]+bhh[g]   (fp16 MFMA)
//   P[b*Tc+tt]         = X_row . w21 + bias2                    (fp32, fused)
// grid=(Tc,2), block=256; tile M=64 x N=128; K-chunks of 32 in LDS.
__global__ __launch_bounds__(256) void gates_gemm_mfma(
    const float* __restrict__ X, const float* __restrict__ W,
    const float* __restrict__ bih, const float* __restrict__ bhh,
    const float* __restrict__ w21, const float* __restrict__ bias2,
    float* __restrict__ G, float* __restrict__ P, int t0, int Tc) {
  __shared__ __align__(16) _Float16 Xs[64][40];
  __shared__ __align__(16) _Float16 Ws[128][40];
  __shared__ float w21s[256];
  const int tid = threadIdx.x;
  const int m0 = blockIdx.x * 64;
  const int n0 = blockIdx.y * 128;
  const int bb = m0 / Tc;
  const int tt0 = m0 - bb * Tc;
  const int w = tid >> 6, l = tid & 63;
  const int lr = l & 15, lk = l >> 4;
  const bool do_pz = (blockIdx.y == 0);

  const int srow = tid >> 2, skq = (tid & 3) * 8;
  const int wri = tid >> 1, wkh = (tid & 1) * 16;
  const float* xrow = X + (size_t)(bb * TT + t0 + tt0 + srow) * 256 + skq;
  const float* wrow = W + (size_t)(n0 + wri) * 257 + wkh;

  w21s[tid] = w21[tid];

  float bsum[8];
#pragma unroll
  for (int nf = 0; nf < 8; ++nf)
    bsum[nf] = bih[n0 + nf * 16 + lr] + bhh[n0 + nf * 16 + lr];

  v4f acc[8];
#pragma unroll
  for (int nf = 0; nf < 8; ++nf) acc[nf] = (v4f){0.f, 0.f, 0.f, 0.f};
  float psum = 0.f;

  for (int k0 = 0; k0 < 256; k0 += 32) {
    float xa[8], wa[16];
#pragma unroll
    for (int u = 0; u < 8; ++u) xa[u] = xrow[k0 + u];
#pragma unroll
    for (int u = 0; u < 16; ++u) wa[u] = wrow[k0 + u];
    if (k0 != 0) __syncthreads();
    {
      uint xw[4];
#pragma unroll
      for (int u = 0; u < 4; ++u) {
        v2h p; p.x = (_Float16)xa[2*u]; p.y = (_Float16)xa[2*u+1];
        xw[u] = __builtin_bit_cast(uint, p);
      }
      *reinterpret_cast<uint4*>(&Xs[srow][skq]) =
          make_uint4(xw[0], xw[1], xw[2], xw[3]);
      uint ww[8];
#pragma unroll
      for (int u = 0; u < 8; ++u) {
        v2h p; p.x = (_Float16)wa[2*u]; p.y = (_Float16)wa[2*u+1];
        ww[u] = __builtin_bit_cast(uint, p);
      }
      *reinterpret_cast<uint4*>(&Ws[wri][wkh]) =
          make_uint4(ww[0], ww[1], ww[2], ww[3]);
      *reinterpret_cast<uint4*>(&Ws[wri][wkh + 8]) =
          make_uint4(ww[4], ww[5], ww[6], ww[7]);
    }
    __syncthreads();
    if (do_pz) {
#pragma unroll
      for (int u = 0; u < 8; ++u) psum += xa[u] * w21s[k0 + skq + u];
    }
    const v4h a0 = *reinterpret_cast<const v4h*>(&Xs[w * 16 + lr][lk * 4]);
    const v4h a1 = *reinterpret_cast<const v4h*>(&Xs[w * 16 + lr][16 + lk * 4]);
#pragma unroll
    for (int nf = 0; nf < 8; ++nf) {
      const v4h b0 = *reinterpret_cast<const v4h*>(&Ws[nf * 16 + lr][lk * 4]);
      const v4h b1 = *reinterpret_cast<const v4h*>(&Ws[nf * 16 + lr][16 + lk * 4]);
      acc[nf] = __builtin_amdgcn_mfma_f32_16x16x16f16(a0, b0, acc[nf], 0, 0, 0);
      acc[nf] = __builtin_amdgcn_mfma_f32_16x16x16f16(a1, b1, acc[nf], 0, 0, 0);
    }
  }
  if (do_pz) {
    psum += __shfl_xor(psum, 1);
    psum += __shfl_xor(psum, 2);
    if ((tid & 3) == 0) P[m0 + srow] = psum + bias2[0];
  }
  const int grow = m0 + w * 16 + lk * 4;
#pragma unroll
  for (int nf = 0; nf < 8; ++nf) {
#pragma unroll
    for (int j = 0; j < 4; ++j) {
      G[(size_t)(grow + j) * 256 + n0 + nf * 16 + lr] = acc[nf][j] + bsum[nf];
    }
  }
}

// Serial recurrence: ONE WAVE PER BLOCK -- R11's lstm_seq7 VERBATIM (951us
// measured, best). R12's 4x8 chain split regressed (+83us): do not touch.
__global__ __launch_bounds__(64, 1) void lstm_seq7(
    const float* __restrict__ G, const float* __restrict__ P,
    const float* __restrict__ Wih, const float* __restrict__ Whh,
    const float* __restrict__ w22, float* __restrict__ Z,
    float* __restrict__ hq, float* __restrict__ cq, int t0, int Tc) {
  const int l = threadIdx.x;         // hidden unit
  const int b = blockIdx.x;          // batch row
  __shared__ __align__(16) _Float16 hsm[64];

  v2h wh[4][32];
#pragma unroll
  for (int q = 0; q < 4; ++q) {
#pragma unroll
    for (int j = 0; j < 16; ++j) {
      float4 v = *reinterpret_cast<const float4*>(&Whh[(size_t)(q*64 + l)*64 + 4*j]);
      v2h pA, pB;
      pA.x = (_Float16)v.x; pA.y = (_Float16)v.y;
      pB.x = (_Float16)v.z; pB.y = (_Float16)v.w;
      wh[q][2*j] = pA; wh[q][2*j+1] = pB;
    }
  }
  float wihL[4];
#pragma unroll
  for (int q = 0; q < 4; ++q) wihL[q] = Wih[(size_t)(q*64 + l)*257 + 256];
  const float w22r = w22[l];

  float h = 0.f, c = 0.f;
  if (t0 != 0) { h = hq[b * 64 + l]; c = cq[b * 64 + l]; }
  hsm[l] = (_Float16)h;
  __builtin_amdgcn_wave_barrier();

  const float* Gb = G + (size_t)b * Tc * 256 + l;
  const float* Pb = P + (size_t)b * Tc;
  float* Zb = Z + (size_t)b * TT + t0;

  float gr[4][4], pr[4];
#pragma unroll
  for (int u = 0; u < 4; ++u) {
    const float* Gt = Gb + (size_t)u * 256;
#pragma unroll
    for (int q = 0; q < 4; ++q) gr[u][q] = Gt[q * 64];
    pr[u] = Pb[u];
  }

  for (int tt = 0; tt < Tc; tt += 4) {
    float zs[4];
#pragma unroll
    for (int uu = 0; uu < 4; ++uu) {
      const int step = tt + uu;
      const float gx0 = gr[uu][0], gx1 = gr[uu][1];
      const float gx2 = gr[uu][2], gx3 = gr[uu][3];
      const float p0 = pr[uu];
      int pf = step + 4; if (pf > Tc - 1) pf = Tc - 1;
      {
        const float* Gt = Gb + (size_t)pf * 256;
#pragma unroll
        for (int q = 0; q < 4; ++q) gr[uu][q] = Gt[q * 64];
        pr[uu] = Pb[pf];
      }

      const float tot = wave_sum64(h * w22r);
      const float pz = fsig(tot + p0);

      float d0a=0.f,d0b=0.f,d1a=0.f,d1b=0.f,d2a=0.f,d2b=0.f,d3a=0.f,d3b=0.f;
      const uint4* hp = reinterpret_cast<const uint4*>(hsm);
#pragma unroll
      for (int jj = 0; jj < 8; ++jj) {
        const uint4 uq = hp[jj];
        const v2h ha = __builtin_bit_cast(v2h, uq.x);
        const v2h hb = __builtin_bit_cast(v2h, uq.y);
        const v2h hc = __builtin_bit_cast(v2h, uq.z);
        const v2h hd = __builtin_bit_cast(v2h, uq.w);
        d0a = FDOT2(ha, wh[0][4*jj+0], d0a); d0b = FDOT2(hb, wh[0][4*jj+1], d0b);
        d0a = FDOT2(hc, wh[0][4*jj+2], d0a); d0b = FDOT2(hd, wh[0][4*jj+3], d0b);
        d1a = FDOT2(ha, wh[1][4*jj+0], d1a); d1b = FDOT2(hb, wh[1][4*jj+1], d1b);
        d1a = FDOT2(hc, wh[1][4*jj+2], d1a); d1b = FDOT2(hd, wh[1][4*jj+3], d1b);
        d2a = FDOT2(ha, wh[2][4*jj+0], d2a); d2b = FDOT2(hb, wh[2][4*jj+1], d2b);
        d2a = FDOT2(hc, wh[2][4*jj+2], d2a); d2b = FDOT2(hd, wh[2][4*jj+3], d2b);
        d3a = FDOT2(ha, wh[3][4*jj+0], d3a); d3b = FDOT2(hb, wh[3][4*jj+1], d3b);
        d3a = FDOT2(hc, wh[3][4*jj+2], d3a); d3b = FDOT2(hd, wh[3][4*jj+3], d3b);
      }
      const float pre0 = gx0 + pz * wihL[0] + (d0a + d0b);
      const float pre1 = gx1 + pz * wihL[1] + (d1a + d1b);
      const float pre2 = gx2 + pz * wihL[2] + (d2a + d2b);
      const float pre3 = gx3 + pz * wihL[3] + (d3a + d3b);

      const float ai = fsig(pre0);
      const float af = fsig(pre1);
      const float ag = ftan(pre2);
      const float ao = fsig(pre3);
      c = af * c + ai * ag;
      h = ao * ftan(c);

      __builtin_amdgcn_wave_barrier();
      hsm[l] = (_Float16)h;
      __builtin_amdgcn_wave_barrier();
      zs[uu] = pz;
    }
    if (l == 0) {
      float4 zo; zo.x = zs[0]; zo.y = zs[1]; zo.z = zs[2]; zo.w = zs[3];
      *reinterpret_cast<float4*>(&Zb[tt]) = zo;
    }
  }
  hq[b * 64 + l] = h;
  cq[b * 64 + l] = c;
}

// Fully-inline fp32 fallback (only if d_ws is too small for a 64-step chunk).
__global__ __launch_bounds__(256) void lstm_fallback(const float* __restrict__ X,
    const float* __restrict__ w21, const float* __restrict__ w22,
    const float* __restrict__ bias2, const float* __restrict__ Wih,
    const float* __restrict__ Whh, const float* __restrict__ bih,
    const float* __restrict__ bhh, float* __restrict__ Z) {
  const int b = blockIdx.x;
  const int g = threadIdx.x;
  const int lane = g & 63;
  __shared__ __align__(16) float h_s[64];
  __shared__ float act_s[256];
  __shared__ __align__(16) float x_s[256];
  __shared__ __align__(16) float w21_s[256];
  float wh[64];
#pragma unroll
  for (int j = 0; j < 64; j += 4) {
    float4 v = *reinterpret_cast<const float4*>(&Whh[(size_t)g*64 + j]);
    wh[j]=v.x; wh[j+1]=v.y; wh[j+2]=v.z; wh[j+3]=v.w;
  }
  const float wihL = Wih[(size_t)g*257 + 256];
  const float bias = bih[g] + bhh[g];
  const float b2 = bias2[0];
  const float w22r = w22[lane];
  w21_s[g] = w21[g];
  if (g < 64) h_s[g] = 0.f;
  float c = 0.f;
  __syncthreads();
  const float* Wr = Wih + (size_t)g * 257;
  for (int t = 0; t < TT; ++t) {
    x_s[g] = X[((size_t)b*TT + t)*256 + g];
    __syncthreads();
    float pv = h_s[lane] * w22r;
    {
      const float4 xq = *reinterpret_cast<const float4*>(&x_s[lane*4]);
      const float4 wq = *reinterpret_cast<const float4*>(&w21_s[lane*4]);
      pv += xq.x*wq.x + xq.y*wq.y + xq.z*wq.z + xq.w*wq.w;
    }
#pragma unroll
    for (int o = 32; o; o >>= 1) pv += __shfl_xor(pv, o);
    const float pz = fsig(pv + b2);
    float a0=0.f, a1=0.f, a2=0.f, a3=0.f;
#pragma unroll
    for (int j = 0; j < 64; j += 4) {
      float4 hv = *reinterpret_cast<const float4*>(&h_s[j]);
      a0 += hv.x*wh[j]; a1 += hv.y*wh[j+1]; a2 += hv.z*wh[j+2]; a3 += hv.w*wh[j+3];
    }
    float xd0=0.f, xd1=0.f, xd2=0.f, xd3=0.f;
    for (int k = 0; k < 256; k += 4) {
      const float4 xq = *reinterpret_cast<const float4*>(&x_s[k]);
      xd0 += xq.x*Wr[k]; xd1 += xq.y*Wr[k+1]; xd2 += xq.z*Wr[k+2]; xd3 += xq.w*Wr[k+3];
    }
    const float pre = bias + pz*wihL + ((a0+a1)+(a2+a3)) + ((xd0+xd1)+(xd2+xd3));
    act_s[g] = ((g >> 6) == 2) ? ftan(pre) : fsig(pre);
    if (g == 0) Z[(size_t)b*TT + t] = pz;
    __syncthreads();
    if (g < 64) {
      const float iv = act_s[g], fv = act_s[64+g], gv = act_s[128+g], ov = act_s[192+g];
      c = fv*c + iv*gv;
      h_s[g] = ov * ftan(c);
    }
    __syncthreads();
  }
}

extern "C" void kernel_launch(void* const* d_in, const int* in_sizes, int n_in,
                              void* d_out, int out_size, void* d_ws, size_t ws_size,
                              hipStream_t stream) {
  const float* X     = (const float*)d_in[0];  // [64,2048,256]
  const float* w21   = (const float*)d_in[1];  // [256]
  const float* w22   = (const float*)d_in[2];  // [64]
  const float* bias2 = (const float*)d_in[3];  // [1]
  const float* Wih   = (const float*)d_in[4];  // [256,257]
  const float* Whh   = (const float*)d_in[5];  // [256,64]
  const float* bih   = (const float*)d_in[6];  // [256]
  const float* bhh   = (const float*)d_in[7];  // [256]
  float* Z = (float*)d_out;                    // [64,2048]

  int Tc = 0;
  for (int cand = 2048; cand >= 64; cand >>= 1) {
    size_t need = (size_t)cand * (64*256*4 + 64*4) + 2*64*64*4;
    if (ws_size >= need) { Tc = cand; break; }
  }
  if (Tc == 0) {
    lstm_fallback<<<dim3(64), dim3(256), 0, stream>>>(X, w21, w22, bias2, Wih, Whh, bih, bhh, Z);
    return;
  }
  float* Gbuf = (float*)d_ws;                       // [64*Tc, 256]
  float* Pbuf = Gbuf + (size_t)64 * Tc * 256;       // [64*Tc]
  float* hq   = Pbuf + (size_t)64 * Tc;             // [64,64]
  float* cq   = hq + 64 * 64;                       // [64,64]
  for (int t0 = 0; t0 < 2048; t0 += Tc) {
    gates_gemm_mfma<<<dim3(Tc, 2), dim3(256), 0, stream>>>(
        X, Wih, bih, bhh, w21, bias2, Gbuf, Pbuf, t0, Tc);
    lstm_seq7<<<dim3(BB), dim3(64), 0, stream>>>(
        Gbuf, Pbuf, Wih, Whh, w22, Z, hq, cq, t0, Tc);
  }
}